// Round 8
// baseline (621.326 us; speedup 1.0000x reference)
//
#include <hip/hip_runtime.h>
#include <hip/hip_bf16.h>

// GCNConv encoder — LDS-multisplit bucketing + flat edge-parallel LDS-atomic gather,
// 16-deep load pipelining (MLP) per 32-lane group.
//   bucket(dst) = dst>>7 (128 dst rows/bucket, NB <= 1024)
//   A-count -> scan -> A-scatter (packed (src<<7)|ldst per bucket, coalesced copy-out)
//   B1s:  per-bucket degree -> dinv (global) + scale h *= dinv in place (fused)
//   B2:   accs[128][32] fp32 in LDS, init = hs[dst row]; flat edges:
//         lane-parallel pk load -> shuffle -> 16 row loads in flight -> 16 ds_add_f32
//         epilogue: out = accs*dinv[dst] + b
//
// ws: dinv[n] f32 | h[n*32] bf16 | bucketed[E] u32 | btot/bstart/bcursor[1024] ~= 14.9 MB

#define LATD 32
#define INCH 128
#define BSH 7
#define BW 128
#define ACHUNK 8192

__device__ __forceinline__ void load_edge(const int* __restrict__ ei, const int* __restrict__ yei,
                                          int e1, int e2, int e, int& src, int& dst) {
    if (e < e1) { src = ei[e]; dst = ei[e1 + e]; }
    else        { int t = e - e1; src = yei[t]; dst = yei[e2 + t]; }
}

// ---------------- GEMM: h = x @ W -> bf16 [n,32] (proven round-5 version) ----------------
__global__ __launch_bounds__(128) void gemm_tile_k(const float* __restrict__ x,
                                                   const float* __restrict__ W,
                                                   __hip_bfloat16* __restrict__ h, int n) {
    __shared__ float xs[64][132];
    __shared__ float Wl[INCH][LATD];
    int tid = threadIdx.x;
    {
        const float4* Wv = (const float4*)W;
        float4* Wlv = (float4*)&Wl[0][0];
#pragma unroll 2
        for (int i = 0; i < 8; ++i) Wlv[tid + 128 * i] = Wv[tid + 128 * i];
    }
    int row0 = blockIdx.x * 64;
#pragma unroll 4
    for (int v = tid; v < 64 * 32; v += 128) {
        int r = v >> 5, kc = v & 31;
        int gr = row0 + r;
        float4 val = make_float4(0.f, 0.f, 0.f, 0.f);
        if (gr < n) val = ((const float4*)(x + (size_t)gr * INCH))[kc];
        *(float4*)&xs[r][kc * 4] = val;
    }
    __syncthreads();
    int c = tid & 7, rr = tid >> 3;
    int j0 = c * 4, r0 = rr * 4;
    float acc[4][4] = {};
#pragma unroll 2
    for (int kk = 0; kk < INCH; kk += 4) {
        float4 w0 = *(const float4*)&Wl[kk + 0][j0];
        float4 w1 = *(const float4*)&Wl[kk + 1][j0];
        float4 w2 = *(const float4*)&Wl[kk + 2][j0];
        float4 w3 = *(const float4*)&Wl[kk + 3][j0];
#pragma unroll
        for (int ri = 0; ri < 4; ++ri) {
            float4 a = *(const float4*)&xs[r0 + ri][kk];
            acc[ri][0] += a.x * w0.x + a.y * w1.x + a.z * w2.x + a.w * w3.x;
            acc[ri][1] += a.x * w0.y + a.y * w1.y + a.z * w2.y + a.w * w3.y;
            acc[ri][2] += a.x * w0.z + a.y * w1.z + a.z * w2.z + a.w * w3.z;
            acc[ri][3] += a.x * w0.w + a.y * w1.w + a.z * w2.w + a.w * w3.w;
        }
    }
#pragma unroll
    for (int ri = 0; ri < 4; ++ri) {
        int gr = row0 + r0 + ri;
        if (gr < n) {
            __hip_bfloat16 tmp[4];
#pragma unroll
            for (int cj = 0; cj < 4; ++cj) tmp[cj] = __float2bfloat16(acc[ri][cj]);
            *(ushort4*)(&h[(size_t)gr * LATD + j0]) = *(const ushort4*)tmp;
        }
    }
}

__global__ void zero_i32_k(int* p, int cnt) {
    int i = blockIdx.x * 256 + threadIdx.x;
    if (i < cnt) p[i] = 0;
}

// ---------------- pass A-count ----------------
__global__ __launch_bounds__(256) void bucket_count_k(const int* __restrict__ ei, const int* __restrict__ yei,
                                                      int e1, int e2, int* __restrict__ btot, int NB) {
    __shared__ int hist[1024];
    int tid = threadIdx.x;
    for (int i = tid; i < NB; i += 256) hist[i] = 0;
    __syncthreads();
    int E = e1 + e2;
    int e0 = blockIdx.x * ACHUNK;
    int m = E - e0; if (m > ACHUNK) m = ACHUNK;
    for (int i = tid; i < m; i += 256) {
        int src, dst; load_edge(ei, yei, e1, e2, e0 + i, src, dst);
        atomicAdd(&hist[dst >> BSH], 1);
    }
    __syncthreads();
    for (int i = tid; i < NB; i += 256)
        if (hist[i]) atomicAdd(&btot[i], hist[i]);
}

// ---------------- scan buckets ----------------
__global__ __launch_bounds__(1024) void scan_buckets_k(const int* __restrict__ btot,
                                                       int* __restrict__ bstart, int* __restrict__ bcursor, int NB) {
    __shared__ int sd[1024];
    int tid = threadIdx.x;
    int v = (tid < NB) ? btot[tid] : 0;
    sd[tid] = v;
    __syncthreads();
    int val = v;
    for (int off = 1; off < 1024; off <<= 1) {
        int t = (tid >= off) ? sd[tid - off] : 0;
        __syncthreads();
        val += t;
        sd[tid] = val;
        __syncthreads();
    }
    if (tid < NB) { int ex = val - v; bstart[tid] = ex; bcursor[tid] = ex; }
}

// ---------------- pass A-scatter ----------------
__global__ __launch_bounds__(256) void passA_scatter_k(const int* __restrict__ ei, const int* __restrict__ yei,
                                                       int e1, int e2, int* __restrict__ bcursor,
                                                       unsigned* __restrict__ bucketed, int NB) {
    __shared__ int hist[1024];
    __shared__ int scanex[1024];
    __shared__ int segb[1024];
    __shared__ int sd[256];
    __shared__ unsigned stage[ACHUNK];
    __shared__ unsigned short bof[ACHUNK];
    int tid = threadIdx.x;
    int E = e1 + e2;
    int e0 = blockIdx.x * ACHUNK;
    int m = E - e0; if (m > ACHUNK) m = ACHUNK;
    for (int i = tid; i < 1024; i += 256) hist[i] = 0;
    __syncthreads();
    for (int i = tid; i < m; i += 256) {
        int src, dst; load_edge(ei, yei, e1, e2, e0 + i, src, dst);
        atomicAdd(&hist[dst >> BSH], 1);
    }
    __syncthreads();
    int b4 = tid * 4;
    int c0 = hist[b4], c1 = hist[b4 + 1], c2 = hist[b4 + 2], c3 = hist[b4 + 3];
    int tot4 = c0 + c1 + c2 + c3;
    sd[tid] = tot4;
    __syncthreads();
    int val = tot4;
    for (int off = 1; off < 256; off <<= 1) {
        int t = (tid >= off) ? sd[tid - off] : 0;
        __syncthreads();
        val += t;
        sd[tid] = val;
        __syncthreads();
    }
    int eb = val - tot4;
    scanex[b4] = eb; scanex[b4 + 1] = eb + c0; scanex[b4 + 2] = eb + c0 + c1; scanex[b4 + 3] = eb + c0 + c1 + c2;
    __syncthreads();
    for (int b = tid; b < NB; b += 256)
        segb[b] = hist[b] ? atomicAdd(&bcursor[b], hist[b]) : 0;
    __syncthreads();
    for (int b = tid; b < 1024; b += 256) hist[b] = scanex[b];
    __syncthreads();
    for (int i = tid; i < m; i += 256) {
        int src, dst; load_edge(ei, yei, e1, e2, e0 + i, src, dst);
        int b = dst >> BSH;
        int pos = atomicAdd(&hist[b], 1);
        stage[pos] = ((unsigned)src << BSH) | (unsigned)(dst & (BW - 1));
        bof[pos] = (unsigned short)b;
    }
    __syncthreads();
    for (int i = tid; i < m; i += 256) {
        int b = bof[i];
        bucketed[segb[b] + (i - scanex[b])] = stage[i];
    }
}

// ---------------- pass B1s: per-bucket degree -> dinv + in-place scale h *= dinv ----------------
__global__ __launch_bounds__(256) void passB1s_k(const unsigned* __restrict__ bucketed,
                                                 const int* __restrict__ bstart, const int* __restrict__ btot,
                                                 float* __restrict__ dinv, unsigned* __restrict__ h2, int n) {
    __shared__ int cnt[BW];
    __shared__ float sdv[BW];
    int tid = threadIdx.x;
    int b = blockIdx.x;
    int s = bstart[b], tot = btot[b];
    int dst0 = b << BSH;
    if (tid < BW) cnt[tid] = 0;
    __syncthreads();
    for (int i = tid; i < tot; i += 256)
        atomicAdd(&cnt[bucketed[s + i] & (BW - 1)], 1);
    __syncthreads();
    if (tid < BW) {
        float dv = rsqrtf((float)cnt[tid] + 1.0f);
        sdv[tid] = dv;
        int node = dst0 + tid;
        if (node < n) dinv[node] = dv;
    }
    __syncthreads();
    // scale 128 rows x 16 uints (bf16x2) in place
    for (int idx = tid; idx < BW * 16; idx += 256) {
        int ldn = idx >> 4;
        int node = dst0 + ldn;
        if (node >= n) continue;
        float dv = sdv[ldn];
        unsigned u = h2[(size_t)node * 16 + (idx & 15)];
        __hip_bfloat162 v = *(__hip_bfloat162*)&u;
        float2 f = __bfloat1622float2(v);
        __hip_bfloat162 r = __float22bfloat162_rn(make_float2(f.x * dv, f.y * dv));
        h2[(size_t)node * 16 + (idx & 15)] = *(unsigned*)&r;
    }
}

// ---------------- pass B2: flat edge-parallel, 16-deep load pipeline + LDS atomics ----------------
__global__ __launch_bounds__(256) void passB2_k(const unsigned* __restrict__ bucketed,
                                                const int* __restrict__ bstart, const int* __restrict__ btot,
                                                const float* __restrict__ dinv,
                                                const __hip_bfloat16* __restrict__ hs,  // pre-scaled h*dinv
                                                const float* __restrict__ bias,
                                                float* __restrict__ out, int n) {
    __shared__ float accs[BW * LATD];   // 16 KB fp32 accumulator tile
    int tid = threadIdx.x;
    int b = blockIdx.x;
    int s = bstart[b], tot = btot[b];
    int dst0 = b << BSH;
    int g = tid >> 5, j = tid & 31;
    // init with self message hs[node][j]
#pragma unroll
    for (int q = 0; q < 16; ++q) {
        int ld = g + q * 8;
        int node = dst0 + ld;
        float v = (node < n) ? __bfloat162float(hs[(size_t)node * LATD + j]) : 0.0f;
        accs[ld * LATD + j] = v;
    }
    __syncthreads();
    // each group takes a contiguous sub-range of the bucket
    int chunk = (tot + 7) >> 3;
    int gs = g * chunk;
    int ge = gs + chunk; if (ge > tot) ge = tot;
    for (int base = gs; base < ge; base += 32) {
        int m = ge - base; if (m > 32) m = 32;
        unsigned myPk = (j < m) ? bucketed[s + base + j] : 0u;   // coalesced 128B/group
        if (m == 32) {
            unsigned pk[16];
            float v[16];
            // half 1: 16 loads in flight, then 16 LDS atomics
#pragma unroll
            for (int t = 0; t < 16; ++t) {
                pk[t] = __shfl(myPk, t, 32);
                v[t] = __bfloat162float(hs[(size_t)(pk[t] >> BSH) * LATD + j]);
            }
#pragma unroll
            for (int t = 0; t < 16; ++t)
                atomicAdd(&accs[(pk[t] & (BW - 1)) * LATD + j], v[t]);
            // half 2
#pragma unroll
            for (int t = 0; t < 16; ++t) {
                pk[t] = __shfl(myPk, t + 16, 32);
                v[t] = __bfloat162float(hs[(size_t)(pk[t] >> BSH) * LATD + j]);
            }
#pragma unroll
            for (int t = 0; t < 16; ++t)
                atomicAdd(&accs[(pk[t] & (BW - 1)) * LATD + j], v[t]);
        } else {
#pragma unroll 4
            for (int t = 0; t < m; ++t) {
                unsigned pkt = __shfl(myPk, t, 32);
                float vt = __bfloat162float(hs[(size_t)(pkt >> BSH) * LATD + j]);
                atomicAdd(&accs[(pkt & (BW - 1)) * LATD + j], vt);
            }
        }
    }
    __syncthreads();
    float bj = bias[j];
#pragma unroll
    for (int q = 0; q < 16; ++q) {
        int ld = g + q * 8;
        int node = dst0 + ld;
        if (node < n)
            out[(size_t)node * LATD + j] = accs[ld * LATD + j] * dinv[node] + bj;
    }
}

// ---------------- fallback path (atomic scatter; uses UNSCALED h) ----------------
__global__ void count_k(const int* __restrict__ ei, const int* __restrict__ yei,
                        int* __restrict__ cnt, int e1, int e2) {
    int e = blockIdx.x * 256 + threadIdx.x;
    if (e >= e1 + e2) return;
    int src, dst; load_edge(ei, yei, e1, e2, e, src, dst);
    atomicAdd(&cnt[dst], 1);
}

__global__ void dinv_k(const int* __restrict__ cnt, float* __restrict__ dinv, int n) {
    int i = blockIdx.x * 256 + threadIdx.x;
    if (i < n) dinv[i] = rsqrtf((float)cnt[i] + 1.0f);
}

__global__ void selfbias_k(const float* __restrict__ dinv, const __hip_bfloat16* __restrict__ h,
                           const float* __restrict__ b, float* __restrict__ out, int total) {
    int idx = blockIdx.x * 256 + threadIdx.x;
    if (idx >= total) return;
    int i = idx >> 5, j = idx & 31;
    float d = dinv[i];
    out[idx] = __bfloat162float(h[idx]) * d * d + b[j];
}

__global__ void scatter_atomic_k(const int* __restrict__ ei, const int* __restrict__ yei,
                                 const float* __restrict__ dinv, const __hip_bfloat16* __restrict__ h,
                                 float* __restrict__ out, int e1, int e2) {
    int idx = blockIdx.x * 256 + threadIdx.x;
    int e = idx >> 5;
    if (e >= e1 + e2) return;
    int j = idx & 31;
    int src, dst; load_edge(ei, yei, e1, e2, e, src, dst);
    float norm = dinv[src] * dinv[dst];
    atomicAdd(&out[(size_t)dst * LATD + j], __bfloat162float(h[(size_t)src * LATD + j]) * norm);
}

static inline size_t aln(size_t x) { return (x + 255) & ~(size_t)255; }

extern "C" void kernel_launch(void* const* d_in, const int* in_sizes, int n_in,
                              void* d_out, int out_size, void* d_ws, size_t ws_size,
                              hipStream_t stream) {
    const float* x  = (const float*)d_in[0];
    const int* ei   = (const int*)d_in[1];
    const int* yei  = (const int*)d_in[2];
    const float* W  = (const float*)d_in[3];
    const float* b  = (const float*)d_in[4];
    float* out = (float*)d_out;

    int n  = in_sizes[0] / INCH;
    int e1 = in_sizes[1] / 2;
    int e2 = in_sizes[2] / 2;
    int E  = e1 + e2;
    int NB = (n + BW - 1) >> BSH;

    char* p = (char*)d_ws;
    size_t off = 0;
    float* dinv = (float*)(p + off);            off += aln((size_t)n * 4);
    __hip_bfloat16* h = (__hip_bfloat16*)(p + off); off += aln((size_t)n * LATD * 2);
    unsigned* bucketed = (unsigned*)(p + off);  size_t bucketed_off = off; off += aln((size_t)E * 4);
    int* btot    = (int*)(p + off); off += aln(1024 * 4);
    int* bstart  = (int*)(p + off); off += aln(1024 * 4);
    int* bcursor = (int*)(p + off); off += aln(1024 * 4);
    bool fast_ok = (off <= ws_size) && (NB <= 1024);

    gemm_tile_k<<<(n + 63) / 64, 128, 0, stream>>>(x, W, h, n);

    if (fast_ok) {
        int ablocks = (E + ACHUNK - 1) / ACHUNK;
        zero_i32_k<<<(NB + 255) / 256, 256, 0, stream>>>(btot, NB);
        bucket_count_k<<<ablocks, 256, 0, stream>>>(ei, yei, e1, e2, btot, NB);
        scan_buckets_k<<<1, 1024, 0, stream>>>(btot, bstart, bcursor, NB);
        passA_scatter_k<<<ablocks, 256, 0, stream>>>(ei, yei, e1, e2, bcursor, bucketed, NB);
        passB1s_k<<<NB, 256, 0, stream>>>(bucketed, bstart, btot, dinv, (unsigned*)h, n);
        passB2_k<<<NB, 256, 0, stream>>>(bucketed, bstart, btot, dinv, h, b, out, n);
    } else {
        int* cnt = (int*)(p + bucketed_off);
        zero_i32_k<<<(n + 255) / 256, 256, 0, stream>>>(cnt, n);
        count_k<<<(E + 255) / 256, 256, 0, stream>>>(ei, yei, cnt, e1, e2);
        dinv_k<<<(n + 255) / 256, 256, 0, stream>>>(cnt, dinv, n);
        selfbias_k<<<(out_size + 255) / 256, 256, 0, stream>>>(dinv, h, b, out, out_size);
        scatter_atomic_k<<<((size_t)E * LATD + 255) / 256, 256, 0, stream>>>(ei, yei, dinv, h, out, e1, e2);
    }
}

// Round 9
// 233.034 us; speedup vs baseline: 2.6662x; 2.6662x over previous
//
#include <hip/hip_runtime.h>
#include <hip/hip_bf16.h>

// GCNConv encoder — LDS-multisplit bucketing + in-LDS counting sort + flat segmented
// gather with register accumulation and boundary-only GLOBAL atomic flushes.
// (R7/R8 lesson: per-edge ds_add_f32 is per-lane serialized ~4cy/lane => ~420us. Avoid.)
//   bucket(dst) = dst>>7 (128 rows/bucket, NB <= 1024)
//   A-count -> scan -> A-scatter (packed (src<<7)|ldst per bucket)
//   B1s:  per-bucket degree -> dinv + scale h *= dinv in place (hs)
//   init: out = hs*dinv + b   (self-loop + bias)
//   B2:   per bucket: counting-sort chunk in LDS; groups sweep sorted edges in
//         full 32-batches (shuffle + row load + FMA into register acc);
//         flush acc*dinv[dst] to out via global atomicAdd at segment boundaries only.
//
// ws: dinv[n] f32 | h[n*32] bf16 | bucketed[E] u32 | btot/bstart/bcursor[1024] ~= 14.9 MB

#define LATD 32
#define INCH 128
#define BSH 7
#define BW 128
#define ACHUNK 8192
#define BCAP 4096

__device__ __forceinline__ void load_edge(const int* __restrict__ ei, const int* __restrict__ yei,
                                          int e1, int e2, int e, int& src, int& dst) {
    if (e < e1) { src = ei[e]; dst = ei[e1 + e]; }
    else        { int t = e - e1; src = yei[t]; dst = yei[e2 + t]; }
}

// ---------------- GEMM: h = x @ W -> bf16 [n,32] (proven round-5 version) ----------------
__global__ __launch_bounds__(128) void gemm_tile_k(const float* __restrict__ x,
                                                   const float* __restrict__ W,
                                                   __hip_bfloat16* __restrict__ h, int n) {
    __shared__ float xs[64][132];
    __shared__ float Wl[INCH][LATD];
    int tid = threadIdx.x;
    {
        const float4* Wv = (const float4*)W;
        float4* Wlv = (float4*)&Wl[0][0];
#pragma unroll 2
        for (int i = 0; i < 8; ++i) Wlv[tid + 128 * i] = Wv[tid + 128 * i];
    }
    int row0 = blockIdx.x * 64;
#pragma unroll 4
    for (int v = tid; v < 64 * 32; v += 128) {
        int r = v >> 5, kc = v & 31;
        int gr = row0 + r;
        float4 val = make_float4(0.f, 0.f, 0.f, 0.f);
        if (gr < n) val = ((const float4*)(x + (size_t)gr * INCH))[kc];
        *(float4*)&xs[r][kc * 4] = val;
    }
    __syncthreads();
    int c = tid & 7, rr = tid >> 3;
    int j0 = c * 4, r0 = rr * 4;
    float acc[4][4] = {};
#pragma unroll 2
    for (int kk = 0; kk < INCH; kk += 4) {
        float4 w0 = *(const float4*)&Wl[kk + 0][j0];
        float4 w1 = *(const float4*)&Wl[kk + 1][j0];
        float4 w2 = *(const float4*)&Wl[kk + 2][j0];
        float4 w3 = *(const float4*)&Wl[kk + 3][j0];
#pragma unroll
        for (int ri = 0; ri < 4; ++ri) {
            float4 a = *(const float4*)&xs[r0 + ri][kk];
            acc[ri][0] += a.x * w0.x + a.y * w1.x + a.z * w2.x + a.w * w3.x;
            acc[ri][1] += a.x * w0.y + a.y * w1.y + a.z * w2.y + a.w * w3.y;
            acc[ri][2] += a.x * w0.z + a.y * w1.z + a.z * w2.z + a.w * w3.z;
            acc[ri][3] += a.x * w0.w + a.y * w1.w + a.z * w2.w + a.w * w3.w;
        }
    }
#pragma unroll
    for (int ri = 0; ri < 4; ++ri) {
        int gr = row0 + r0 + ri;
        if (gr < n) {
            __hip_bfloat16 tmp[4];
#pragma unroll
            for (int cj = 0; cj < 4; ++cj) tmp[cj] = __float2bfloat16(acc[ri][cj]);
            *(ushort4*)(&h[(size_t)gr * LATD + j0]) = *(const ushort4*)tmp;
        }
    }
}

__global__ void zero_i32_k(int* p, int cnt) {
    int i = blockIdx.x * 256 + threadIdx.x;
    if (i < cnt) p[i] = 0;
}

// ---------------- pass A-count ----------------
__global__ __launch_bounds__(256) void bucket_count_k(const int* __restrict__ ei, const int* __restrict__ yei,
                                                      int e1, int e2, int* __restrict__ btot, int NB) {
    __shared__ int hist[1024];
    int tid = threadIdx.x;
    for (int i = tid; i < NB; i += 256) hist[i] = 0;
    __syncthreads();
    int E = e1 + e2;
    int e0 = blockIdx.x * ACHUNK;
    int m = E - e0; if (m > ACHUNK) m = ACHUNK;
    for (int i = tid; i < m; i += 256) {
        int src, dst; load_edge(ei, yei, e1, e2, e0 + i, src, dst);
        atomicAdd(&hist[dst >> BSH], 1);
    }
    __syncthreads();
    for (int i = tid; i < NB; i += 256)
        if (hist[i]) atomicAdd(&btot[i], hist[i]);
}

// ---------------- scan buckets ----------------
__global__ __launch_bounds__(1024) void scan_buckets_k(const int* __restrict__ btot,
                                                       int* __restrict__ bstart, int* __restrict__ bcursor, int NB) {
    __shared__ int sd[1024];
    int tid = threadIdx.x;
    int v = (tid < NB) ? btot[tid] : 0;
    sd[tid] = v;
    __syncthreads();
    int val = v;
    for (int off = 1; off < 1024; off <<= 1) {
        int t = (tid >= off) ? sd[tid - off] : 0;
        __syncthreads();
        val += t;
        sd[tid] = val;
        __syncthreads();
    }
    if (tid < NB) { int ex = val - v; bstart[tid] = ex; bcursor[tid] = ex; }
}

// ---------------- pass A-scatter ----------------
__global__ __launch_bounds__(256) void passA_scatter_k(const int* __restrict__ ei, const int* __restrict__ yei,
                                                       int e1, int e2, int* __restrict__ bcursor,
                                                       unsigned* __restrict__ bucketed, int NB) {
    __shared__ int hist[1024];
    __shared__ int scanex[1024];
    __shared__ int segb[1024];
    __shared__ int sd[256];
    __shared__ unsigned stage[ACHUNK];
    __shared__ unsigned short bof[ACHUNK];
    int tid = threadIdx.x;
    int E = e1 + e2;
    int e0 = blockIdx.x * ACHUNK;
    int m = E - e0; if (m > ACHUNK) m = ACHUNK;
    for (int i = tid; i < 1024; i += 256) hist[i] = 0;
    __syncthreads();
    for (int i = tid; i < m; i += 256) {
        int src, dst; load_edge(ei, yei, e1, e2, e0 + i, src, dst);
        atomicAdd(&hist[dst >> BSH], 1);
    }
    __syncthreads();
    int b4 = tid * 4;
    int c0 = hist[b4], c1 = hist[b4 + 1], c2 = hist[b4 + 2], c3 = hist[b4 + 3];
    int tot4 = c0 + c1 + c2 + c3;
    sd[tid] = tot4;
    __syncthreads();
    int val = tot4;
    for (int off = 1; off < 256; off <<= 1) {
        int t = (tid >= off) ? sd[tid - off] : 0;
        __syncthreads();
        val += t;
        sd[tid] = val;
        __syncthreads();
    }
    int eb = val - tot4;
    scanex[b4] = eb; scanex[b4 + 1] = eb + c0; scanex[b4 + 2] = eb + c0 + c1; scanex[b4 + 3] = eb + c0 + c1 + c2;
    __syncthreads();
    for (int b = tid; b < NB; b += 256)
        segb[b] = hist[b] ? atomicAdd(&bcursor[b], hist[b]) : 0;
    __syncthreads();
    for (int b = tid; b < 1024; b += 256) hist[b] = scanex[b];
    __syncthreads();
    for (int i = tid; i < m; i += 256) {
        int src, dst; load_edge(ei, yei, e1, e2, e0 + i, src, dst);
        int b = dst >> BSH;
        int pos = atomicAdd(&hist[b], 1);
        stage[pos] = ((unsigned)src << BSH) | (unsigned)(dst & (BW - 1));
        bof[pos] = (unsigned short)b;
    }
    __syncthreads();
    for (int i = tid; i < m; i += 256) {
        int b = bof[i];
        bucketed[segb[b] + (i - scanex[b])] = stage[i];
    }
}

// ---------------- pass B1s: per-bucket degree -> dinv + in-place scale h *= dinv ----------------
__global__ __launch_bounds__(256) void passB1s_k(const unsigned* __restrict__ bucketed,
                                                 const int* __restrict__ bstart, const int* __restrict__ btot,
                                                 float* __restrict__ dinv, unsigned* __restrict__ h2, int n) {
    __shared__ int cnt[BW];
    __shared__ float sdv[BW];
    int tid = threadIdx.x;
    int b = blockIdx.x;
    int s = bstart[b], tot = btot[b];
    int dst0 = b << BSH;
    if (tid < BW) cnt[tid] = 0;
    __syncthreads();
    for (int i = tid; i < tot; i += 256)
        atomicAdd(&cnt[bucketed[s + i] & (BW - 1)], 1);
    __syncthreads();
    if (tid < BW) {
        float dv = rsqrtf((float)cnt[tid] + 1.0f);
        sdv[tid] = dv;
        int node = dst0 + tid;
        if (node < n) dinv[node] = dv;
    }
    __syncthreads();
    for (int idx = tid; idx < BW * 16; idx += 256) {
        int ldn = idx >> 4;
        int node = dst0 + ldn;
        if (node >= n) continue;
        float dv = sdv[ldn];
        unsigned u = h2[(size_t)node * 16 + (idx & 15)];
        __hip_bfloat162 v = *(__hip_bfloat162*)&u;
        float2 f = __bfloat1622float2(v);
        __hip_bfloat162 r = __float22bfloat162_rn(make_float2(f.x * dv, f.y * dv));
        h2[(size_t)node * 16 + (idx & 15)] = *(unsigned*)&r;
    }
}

// ---------------- init: out = hs*dinv + b  (self-loop + bias) ----------------
__global__ void init_out_k(const float* __restrict__ dinv, const __hip_bfloat16* __restrict__ hs,
                           const float* __restrict__ b, float* __restrict__ out, int total) {
    int idx = blockIdx.x * 256 + threadIdx.x;
    if (idx >= total) return;
    int i = idx >> 5, j = idx & 31;
    out[idx] = __bfloat162float(hs[idx]) * dinv[i] + b[j];
}

// ---------------- pass B2: sort chunk in LDS, flat segmented gather, global flush ----------------
__global__ __launch_bounds__(256) void passB2_k(const unsigned* __restrict__ bucketed,
                                                const int* __restrict__ bstart, const int* __restrict__ btot,
                                                const float* __restrict__ dinv,
                                                const __hip_bfloat16* __restrict__ hs,  // pre-scaled h*dinv
                                                float* __restrict__ out, int n) {
    __shared__ int cnt[BW], rowoff[BW], cur[BW];
    __shared__ unsigned stage[BCAP];
    int tid = threadIdx.x;
    int b = blockIdx.x;
    int s = bstart[b], tot = btot[b];
    int dst0 = b << BSH;
    int g = tid >> 5, j = tid & 31;

    for (int c0 = 0; c0 < tot; c0 += BCAP) {
        int m = tot - c0; if (m > BCAP) m = BCAP;
        // ---- counting sort of chunk by local dst ----
        if (tid < BW) cnt[tid] = 0;
        __syncthreads();
        for (int i = tid; i < m; i += 256)
            atomicAdd(&cnt[bucketed[s + c0 + i] & (BW - 1)], 1);
        __syncthreads();
        if (tid < BW) rowoff[tid] = cnt[tid];
        __syncthreads();
        for (int off = 1; off < BW; off <<= 1) {
            int t = 0;
            if (tid < BW && tid >= off) t = rowoff[tid - off];
            __syncthreads();
            if (tid < BW) rowoff[tid] += t;
            __syncthreads();
        }
        if (tid < BW) cur[tid] = rowoff[tid] - cnt[tid];
        __syncthreads();
        for (int i = tid; i < m; i += 256) {
            unsigned e = bucketed[s + c0 + i];
            int p = atomicAdd(&cur[e & (BW - 1)], 1);
            stage[p] = e;    // packed (src<<7)|ldst, now sorted by ldst
        }
        __syncthreads();
        // ---- flat segmented gather over sorted stage[0..m) ----
        int chunk = (((m + 7) >> 3) + 31) & ~31;   // 32-aligned contiguous range per group
        int gs = g * chunk;
        int ge = gs + chunk; if (ge > m) ge = m;
        float acc = 0.0f;
        int cur_ld = -1;
        for (int base = gs; base < ge; base += 32) {
            int mm = ge - base; if (mm > 32) mm = 32;
            unsigned myPk = (j < mm) ? stage[base + j] : 0u;
            if (mm == 32) {
#pragma unroll
                for (int ph = 0; ph < 4; ++ph) {
                    unsigned pk8[8]; float v8[8];
#pragma unroll
                    for (int t = 0; t < 8; ++t) {
                        pk8[t] = __shfl(myPk, ph * 8 + t, 32);
                        v8[t] = __bfloat162float(hs[(size_t)(pk8[t] >> BSH) * LATD + j]);
                    }
#pragma unroll
                    for (int t = 0; t < 8; ++t) {
                        int ld = (int)(pk8[t] & (BW - 1));
                        if (ld != cur_ld) {
                            if (cur_ld >= 0) {
                                int node = dst0 + cur_ld;
                                atomicAdd(&out[(size_t)node * LATD + j], acc * dinv[node]);
                            }
                            cur_ld = ld; acc = 0.0f;
                        }
                        acc += v8[t];
                    }
                }
            } else {
#pragma unroll 4
                for (int t = 0; t < mm; ++t) {
                    unsigned pk = __shfl(myPk, t, 32);
                    float v = __bfloat162float(hs[(size_t)(pk >> BSH) * LATD + j]);
                    int ld = (int)(pk & (BW - 1));
                    if (ld != cur_ld) {
                        if (cur_ld >= 0) {
                            int node = dst0 + cur_ld;
                            atomicAdd(&out[(size_t)node * LATD + j], acc * dinv[node]);
                        }
                        cur_ld = ld; acc = 0.0f;
                    }
                    acc += v;
                }
            }
        }
        if (cur_ld >= 0) {
            int node = dst0 + cur_ld;
            atomicAdd(&out[(size_t)node * LATD + j], acc * dinv[node]);
        }
        __syncthreads();   // before next chunk reuses cnt/stage
    }
}

// ---------------- fallback path (atomic scatter; uses UNSCALED h) ----------------
__global__ void count_k(const int* __restrict__ ei, const int* __restrict__ yei,
                        int* __restrict__ cnt, int e1, int e2) {
    int e = blockIdx.x * 256 + threadIdx.x;
    if (e >= e1 + e2) return;
    int src, dst; load_edge(ei, yei, e1, e2, e, src, dst);
    atomicAdd(&cnt[dst], 1);
}

__global__ void dinv_k(const int* __restrict__ cnt, float* __restrict__ dinv, int n) {
    int i = blockIdx.x * 256 + threadIdx.x;
    if (i < n) dinv[i] = rsqrtf((float)cnt[i] + 1.0f);
}

__global__ void selfbias_k(const float* __restrict__ dinv, const __hip_bfloat16* __restrict__ h,
                           const float* __restrict__ b, float* __restrict__ out, int total) {
    int idx = blockIdx.x * 256 + threadIdx.x;
    if (idx >= total) return;
    int i = idx >> 5, j = idx & 31;
    float d = dinv[i];
    out[idx] = __bfloat162float(h[idx]) * d * d + b[j];
}

__global__ void scatter_atomic_k(const int* __restrict__ ei, const int* __restrict__ yei,
                                 const float* __restrict__ dinv, const __hip_bfloat16* __restrict__ h,
                                 float* __restrict__ out, int e1, int e2) {
    int idx = blockIdx.x * 256 + threadIdx.x;
    int e = idx >> 5;
    if (e >= e1 + e2) return;
    int j = idx & 31;
    int src, dst; load_edge(ei, yei, e1, e2, e, src, dst);
    float norm = dinv[src] * dinv[dst];
    atomicAdd(&out[(size_t)dst * LATD + j], __bfloat162float(h[(size_t)src * LATD + j]) * norm);
}

static inline size_t aln(size_t x) { return (x + 255) & ~(size_t)255; }

extern "C" void kernel_launch(void* const* d_in, const int* in_sizes, int n_in,
                              void* d_out, int out_size, void* d_ws, size_t ws_size,
                              hipStream_t stream) {
    const float* x  = (const float*)d_in[0];
    const int* ei   = (const int*)d_in[1];
    const int* yei  = (const int*)d_in[2];
    const float* W  = (const float*)d_in[3];
    const float* b  = (const float*)d_in[4];
    float* out = (float*)d_out;

    int n  = in_sizes[0] / INCH;
    int e1 = in_sizes[1] / 2;
    int e2 = in_sizes[2] / 2;
    int E  = e1 + e2;
    int NB = (n + BW - 1) >> BSH;

    char* p = (char*)d_ws;
    size_t off = 0;
    float* dinv = (float*)(p + off);            off += aln((size_t)n * 4);
    __hip_bfloat16* h = (__hip_bfloat16*)(p + off); off += aln((size_t)n * LATD * 2);
    unsigned* bucketed = (unsigned*)(p + off);  size_t bucketed_off = off; off += aln((size_t)E * 4);
    int* btot    = (int*)(p + off); off += aln(1024 * 4);
    int* bstart  = (int*)(p + off); off += aln(1024 * 4);
    int* bcursor = (int*)(p + off); off += aln(1024 * 4);
    bool fast_ok = (off <= ws_size) && (NB <= 1024);

    gemm_tile_k<<<(n + 63) / 64, 128, 0, stream>>>(x, W, h, n);

    if (fast_ok) {
        int ablocks = (E + ACHUNK - 1) / ACHUNK;
        zero_i32_k<<<(NB + 255) / 256, 256, 0, stream>>>(btot, NB);
        bucket_count_k<<<ablocks, 256, 0, stream>>>(ei, yei, e1, e2, btot, NB);
        scan_buckets_k<<<1, 1024, 0, stream>>>(btot, bstart, bcursor, NB);
        passA_scatter_k<<<ablocks, 256, 0, stream>>>(ei, yei, e1, e2, bcursor, bucketed, NB);
        passB1s_k<<<NB, 256, 0, stream>>>(bucketed, bstart, btot, dinv, (unsigned*)h, n);
        init_out_k<<<(out_size + 255) / 256, 256, 0, stream>>>(dinv, h, b, out, out_size);
        passB2_k<<<NB, 256, 0, stream>>>(bucketed, bstart, btot, dinv, h, out, n);
    } else {
        int* cnt = (int*)(p + bucketed_off);
        zero_i32_k<<<(n + 255) / 256, 256, 0, stream>>>(cnt, n);
        count_k<<<(E + 255) / 256, 256, 0, stream>>>(ei, yei, cnt, e1, e2);
        dinv_k<<<(n + 255) / 256, 256, 0, stream>>>(cnt, dinv, n);
        selfbias_k<<<(out_size + 255) / 256, 256, 0, stream>>>(dinv, h, b, out, out_size);
        scatter_atomic_k<<<((size_t)E * LATD + 255) / 256, 256, 0, stream>>>(ei, yei, dinv, h, out, e1, e2);
    }
}